// Round 7
// baseline (223.917 us; speedup 1.0000x reference)
//
#include <hip/hip_runtime.h>

#define Bc 2
#define Tc 2048
#define Cc 1024
#define Hc 16
#define Dc 64
#define Mtot (Bc*Tc)   // 4096
#define Kdim Cc        // 1024
#define N1 (3*Cc)      // 3072
#define N2 Cc          // 1024

typedef __attribute__((ext_vector_type(8))) short short8;
typedef __attribute__((ext_vector_type(4))) float float4v;

__device__ __forceinline__ unsigned short f2bf(float f) {
  unsigned int u = __builtin_bit_cast(unsigned int, f);
  u += 0x7FFFu + ((u >> 16) & 1u);   // RNE
  return (unsigned short)(u >> 16);
}

// packed f32x2 -> bf16x2 (low=a, high=b)
__device__ __forceinline__ unsigned int pk_bf16(float a, float b) {
#if __has_builtin(__builtin_amdgcn_cvt_pk_bf16_f32)
  typedef __attribute__((ext_vector_type(2))) __bf16 bf16x2;
  bf16x2 v = __builtin_amdgcn_cvt_pk_bf16_f32(a, b);
  return __builtin_bit_cast(unsigned int, v);
#else
  return (unsigned int)f2bf(a) | ((unsigned int)f2bf(b) << 16);
#endif
}

// async global->LDS, 16B per lane. LDS dest must be wave-uniform base + lane*16.
__device__ __forceinline__ void gl2lds16(const unsigned short* g, unsigned short* l) {
  __builtin_amdgcn_global_load_lds((const __attribute__((address_space(1))) void*)g,
                                   (__attribute__((address_space(3))) void*)l, 16, 0, 0);
}

// ---- merged prep: transpose+convert Wqkv and Wout, [K,N] fp32 -> [N,K] bf16 ----
// grid (128, 32): x<96 -> Wqkv tile col, else Wout. 32x32 fp32 tiles.
__global__ __launch_bounds__(256) void k_prep(const float* __restrict__ wqkv,
                                              const float* __restrict__ wout,
                                              unsigned short* __restrict__ wqkvT,
                                              unsigned short* __restrict__ woutT) {
  __shared__ float tile[32][33];
  const int bx = blockIdx.x;
  const float* w;  unsigned short* wT;  int N, n0;
  if (bx < 96) { w = wqkv; wT = wqkvT; N = N1; n0 = bx * 32; }
  else         { w = wout; wT = woutT; N = N2; n0 = (bx - 96) * 32; }
  const int k0 = blockIdx.y * 32;
  int tx = threadIdx.x & 31, ty = threadIdx.x >> 5;   // 32 x 8
  for (int i = 0; i < 4; ++i)
    tile[ty + 8*i][tx] = w[(size_t)(k0 + ty + 8*i) * N + n0 + tx];
  __syncthreads();
  for (int i = 0; i < 4; ++i)
    wT[(size_t)(n0 + ty + 8*i) * Kdim + k0 + tx] = f2bf(tile[tx][ty + 8*i]);
}

// ---- GEMM1: qkv = x @ Wqkv + bqkv; q,k -> [B,H,T,D], v -> [B,H,D,T] (transposed) ----
// A staged DIRECTLY from fp32 x (load+cvt+ds_write); B via global_load_lds.
// scale 1/sqrt(D)=0.125 folded into q. s = n0>>10 block-uniform.
__global__ __launch_bounds__(256) void k_gemm_qkv(const float* __restrict__ X,
                                                  const unsigned short* __restrict__ BT,
                                                  const float* __restrict__ bias,
                                                  unsigned short* __restrict__ qkv) {
  __shared__ alignas(16) unsigned short smem[64*136 + 64];  // >= As+Bs (8192); V-bounce 64x136
  unsigned short* As = smem;
  unsigned short* Bs = smem + 4096;
  const int m0 = blockIdx.y * 128, n0 = blockIdx.x * 128;
  const int tid = threadIdx.x;
  const int w = tid >> 6, lane = tid & 63;
  const int ln = lane & 15, qd = lane >> 4;
  const int wm = w >> 1, wn = w & 1;
  const int c0 = tid, c1 = tid + 256;
  const int row0 = c0 >> 2, ko0 = (c0 & 3) * 8;
  const int row1 = c1 >> 2, ko1 = (c1 & 3) * 8;
  const float4v zero4 = {0.f, 0.f, 0.f, 0.f};
  float4v acc[4][4];
  for (int i = 0; i < 4; ++i) for (int j = 0; j < 4; ++j) acc[i][j] = zero4;
  for (int kk = 0; kk < Kdim; kk += 32) {
    __syncthreads();
    float4 a0 = *(const float4*)(X + (size_t)(m0 + row0) * Kdim + kk + ko0);
    float4 a1 = *(const float4*)(X + (size_t)(m0 + row0) * Kdim + kk + ko0 + 4);
    float4 a2 = *(const float4*)(X + (size_t)(m0 + row1) * Kdim + kk + ko1);
    float4 a3 = *(const float4*)(X + (size_t)(m0 + row1) * Kdim + kk + ko1 + 4);
    gl2lds16(BT + (size_t)(n0 + row0) * Kdim + kk + ko0, Bs + c0 * 8);
    gl2lds16(BT + (size_t)(n0 + row1) * Kdim + kk + ko1, Bs + c1 * 8);
    uint4 p0, p1;
    p0.x = pk_bf16(a0.x, a0.y); p0.y = pk_bf16(a0.z, a0.w);
    p0.z = pk_bf16(a1.x, a1.y); p0.w = pk_bf16(a1.z, a1.w);
    p1.x = pk_bf16(a2.x, a2.y); p1.y = pk_bf16(a2.z, a2.w);
    p1.z = pk_bf16(a3.x, a3.y); p1.w = pk_bf16(a3.z, a3.w);
    *(uint4*)(As + c0 * 8) = p0;
    *(uint4*)(As + c1 * 8) = p1;
    __syncthreads();
    short8 af[4], bf[4];
    for (int i = 0; i < 4; ++i)
      af[i] = *(const short8*)(As + (wm*64 + i*16 + ln) * 32 + qd*8);
    for (int j = 0; j < 4; ++j)
      bf[j] = *(const short8*)(Bs + (wn*64 + j*16 + ln) * 32 + qd*8);
    for (int i = 0; i < 4; ++i)
      for (int j = 0; j < 4; ++j)
        acc[i][j] = __builtin_amdgcn_mfma_f32_16x16x32_bf16(af[i], bf[j], acc[i][j], 0, 0, 0);
  }
  const int s = n0 >> 10;
  if (s < 2) {
    const float scale = (s == 0) ? 0.125f : 1.0f;
    for (int i = 0; i < 4; ++i) {
      int mbase = m0 + wm*64 + i*16 + qd*4;
      for (int j = 0; j < 4; ++j) {
        int ncol = n0 + wn*64 + j*16 + ln;
        float bv = bias[ncol];
        int rem = ncol & 1023;
        int h = rem >> 6, d = rem & 63;
        for (int r = 0; r < 4; ++r) {
          int m = mbase + r;
          int b = m >> 11, t = m & 2047;
          float val = (acc[i][j][r] + bv) * scale;
          qkv[((((size_t)s*Bc + b)*Hc + h)*Tc + t)*Dc + d] = f2bf(val);
        }
      }
    }
  } else {
    // V: two head-phases through LDS for coalesced [D,T] stores
    unsigned short* vbase = qkv + (size_t)2*Bc*Hc*Tc*Dc;
    const int b = m0 >> 11, t0 = m0 & 2047;
    const int h0 = (n0 & 1023) >> 6;
    for (int p = 0; p < 2; ++p) {
      __syncthreads();
      if (wn == p) {
        for (int i = 0; i < 4; ++i) {
          int tl = wm*64 + i*16 + qd*4;
          for (int j = 0; j < 4; ++j) {
            int dl = j*16 + ln;
            float bv = bias[n0 + p*64 + dl];
            uint2 pk;
            pk.x = pk_bf16(acc[i][j][0] + bv, acc[i][j][1] + bv);
            pk.y = pk_bf16(acc[i][j][2] + bv, acc[i][j][3] + bv);
            *(uint2*)(smem + dl*136 + tl) = pk;
          }
        }
      }
      __syncthreads();
      for (int ii = 0; ii < 4; ++ii) {
        int idx = tid + 256*ii;
        int row = idx >> 4, c16 = idx & 15;
        int4 v = *(const int4*)(smem + row*136 + c16*8);
        *(int4*)(vbase + (((size_t)b*Hc + h0 + p)*Dc + row)*Tc + t0 + c16*8) = v;
      }
    }
  }
}

// ---- GEMM2: out = attn @ Wout + bout, fp32 out. 64x128 tile -> 512 blocks (2/CU) ----
__global__ __launch_bounds__(256) void k_gemm_out(const unsigned short* __restrict__ A,
                                                  const unsigned short* __restrict__ BT,
                                                  const float* __restrict__ bias,
                                                  float* __restrict__ out) {
  __shared__ alignas(16) unsigned short As[64*32];    // 64 m-rows x 32 k
  __shared__ alignas(16) unsigned short Bs[128*32];   // 128 n-rows x 32 k
  const int m0 = blockIdx.y * 64, n0 = blockIdx.x * 128;
  const int tid = threadIdx.x;
  const int w = tid >> 6, lane = tid & 63;
  const int ln = lane & 15, qd = lane >> 4;
  const int wm = w >> 1, wn = w & 1;                  // wave = 32 m x 64 n
  const int arow = tid >> 2, ako = (tid & 3) * 8;     // As: 256 int4, 1/thread
  const int c0 = tid, c1 = tid + 256;                 // Bs: 512 int4, 2/thread
  const int brow0 = c0 >> 2, bko0 = (c0 & 3) * 8;
  const int brow1 = c1 >> 2, bko1 = (c1 & 3) * 8;
  const float4v zero4 = {0.f, 0.f, 0.f, 0.f};
  float4v acc[2][4];
  for (int i = 0; i < 2; ++i) for (int j = 0; j < 4; ++j) acc[i][j] = zero4;
  for (int kk = 0; kk < Kdim; kk += 32) {
    __syncthreads();
    gl2lds16(A  + (size_t)(m0 + arow)  * Kdim + kk + ako,  As + tid * 8);
    gl2lds16(BT + (size_t)(n0 + brow0) * Kdim + kk + bko0, Bs + c0 * 8);
    gl2lds16(BT + (size_t)(n0 + brow1) * Kdim + kk + bko1, Bs + c1 * 8);
    __syncthreads();
    short8 af[2], bf[4];
    for (int i = 0; i < 2; ++i)
      af[i] = *(const short8*)(As + (wm*32 + i*16 + ln) * 32 + qd*8);
    for (int j = 0; j < 4; ++j)
      bf[j] = *(const short8*)(Bs + (wn*64 + j*16 + ln) * 32 + qd*8);
    for (int i = 0; i < 2; ++i)
      for (int j = 0; j < 4; ++j)
        acc[i][j] = __builtin_amdgcn_mfma_f32_16x16x32_bf16(af[i], bf[j], acc[i][j], 0, 0, 0);
  }
  for (int i = 0; i < 2; ++i) {
    int mbase = m0 + wm*32 + i*16 + qd*4;
    for (int j = 0; j < 4; ++j) {
      int ncol = n0 + wn*64 + j*16 + ln;
      float bv = bias[ncol];
      for (int r = 0; r < 4; ++r)
        out[(size_t)(mbase + r) * N2 + ncol] = acc[i][j][r] + bv;
    }
  }
}

// ---- one online-softmax sub-step for a 16-q-row group against keys [k0,k0+64) ----
__device__ __forceinline__ void attn_substep(
    const unsigned short* __restrict__ Ks, const unsigned short* __restrict__ Vt,
    unsigned short* __restrict__ pw,
    const short8 qa0, const short8 qa1,
    float4v* o, float& m_i, float& l_i,
    int k0, int myq, bool mask, int ln, int qd)
{
  const float L2E = 1.44269504f;
  const float4v zero4 = {0.f, 0.f, 0.f, 0.f};
  float4v s[4];
  for (int ki = 0; ki < 4; ++ki) {
    s[ki] = zero4;
    const unsigned short* kr = Ks + (ki*16 + ln)*72;
    short8 kf0 = *(const short8*)(kr + qd*8);
    short8 kf1 = *(const short8*)(kr + 32 + qd*8);
    s[ki] = __builtin_amdgcn_mfma_f32_16x16x32_bf16(kf0, qa0, s[ki], 0, 0, 0);
    s[ki] = __builtin_amdgcn_mfma_f32_16x16x32_bf16(kf1, qa1, s[ki], 0, 0, 0);
  }
  if (mask) {
    for (int ki = 0; ki < 4; ++ki) {
      int key = k0 + ki*16 + qd*4;
      for (int r = 0; r < 4; ++r)
        if (key + r > myq) s[ki][r] = -1e30f;
    }
  }
  float mt = -1e30f;
  for (int ki = 0; ki < 4; ++ki)
    for (int r = 0; r < 4; ++r) mt = fmaxf(mt, s[ki][r]);
  mt = fmaxf(mt, __shfl_xor(mt, 16));
  mt = fmaxf(mt, __shfl_xor(mt, 32));
  float mn = fmaxf(m_i, mt);
  float al = exp2f((m_i - mn) * L2E);
  m_i = mn;
  float st = 0.f;
  for (int ki = 0; ki < 4; ++ki)
    for (int r = 0; r < 4; ++r) {
      s[ki][r] = exp2f((s[ki][r] - mn) * L2E);
      st += s[ki][r];
    }
  st += __shfl_xor(st, 16);
  st += __shfl_xor(st, 32);
  l_i = l_i * al + st;
  for (int dt = 0; dt < 4; ++dt)
    for (int r = 0; r < 4; ++r) o[dt][r] *= al;
  // P: C/D -> A-operand layout via per-wave LDS buffer (DS in-order per wave)
  for (int ki = 0; ki < 4; ++ki) {
    uint2 p2;
    p2.x = pk_bf16(s[ki][0], s[ki][1]);
    p2.y = pk_bf16(s[ki][2], s[ki][3]);
    *(uint2*)(pw + ln*72 + ki*16 + qd*4) = p2;
  }
  short8 pb0 = *(const short8*)(pw + ln*72 + qd*8);
  short8 pb1 = *(const short8*)(pw + ln*72 + 32 + qd*8);
  for (int dt = 0; dt < 4; ++dt) {
    const unsigned short* vr = Vt + (dt*16 + ln)*72;
    short8 va0 = *(const short8*)(vr + qd*8);
    short8 va1 = *(const short8*)(vr + 32 + qd*8);
    o[dt] = __builtin_amdgcn_mfma_f32_16x16x32_bf16(va0, pb0, o[dt], 0, 0, 0);
    o[dt] = __builtin_amdgcn_mfma_f32_16x16x32_bf16(va1, pb1, o[dt], 0, 0, 0);
  }
}

// ---- flash-style causal attention: dual q-tiles per block, double-buffered K/V ----
// grid (32 bh, 16 pp). Block owns q-tiles A=31-pp (heavy) and B=pp (light) -> 33
// uniform sub-steps. K/V double-buffered in LDS: ONE barrier per kt. Next tile's
// K/V register-prefetched and written into the idle buffer.
__global__ __launch_bounds__(256) void k_attn(const unsigned short* __restrict__ qb,
                                              const unsigned short* __restrict__ kb,
                                              const unsigned short* __restrict__ vT,
                                              unsigned short* __restrict__ ob) {
  __shared__ alignas(16) unsigned short Ks[2][64*72];  // [key][d], stride 72
  __shared__ alignas(16) unsigned short Vt[2][64*72];  // [d][key], stride 72
  __shared__ alignas(16) unsigned short Ps[4][16*72];  // per-wave P, stride 72
  const int bh = blockIdx.x;
  const int pp = blockIdx.y;
  const int qtA = 31 - pp, qtB = pp;
  const int tid = threadIdx.x;
  const int w = tid >> 6, lane = tid & 63;
  const int ln = lane & 15, qd = lane >> 4;
  const size_t base = (size_t)bh * Tc * Dc;
  const int b = bh >> 4, h = bh & 15;
  const int srow = tid >> 3, scol = (tid & 7) * 8;     // staging: 32 rows x 8 int4
  const float4v zero4 = {0.f, 0.f, 0.f, 0.f};
  unsigned short* pw = Ps[w];

  const int myqA = qtA*64 + w*16 + ln;
  const int myqB = qtB*64 + w*16 + ln;
  const unsigned short* qrA = qb + base + (size_t)myqA * Dc;
  const unsigned short* qrB = qb + base + (size_t)myqB * Dc;
  short8 qaA0 = *(const short8*)(qrA + qd*8);
  short8 qaA1 = *(const short8*)(qrA + 32 + qd*8);
  short8 qaB0 = *(const short8*)(qrB + qd*8);
  short8 qaB1 = *(const short8*)(qrB + 32 + qd*8);
  float4v oA[4], oB[4];
  for (int dt = 0; dt < 4; ++dt) { oA[dt] = zero4; oB[dt] = zero4; }
  float mA = -1e30f, lA = 0.f, mB = -1e30f, lB = 0.f;

  // stage kt=0 into buffer 0
  {
    int4 k0v = *(const int4*)(kb + base + (size_t)srow * Dc + scol);
    int4 k1v = *(const int4*)(kb + base + (size_t)(srow + 32) * Dc + scol);
    int4 v0v = *(const int4*)(vT + base + (size_t)srow * Tc + scol);
    int4 v1v = *(const int4*)(vT + base + (size_t)(srow + 32) * Tc + scol);
    *(int4*)(Ks[0] + srow*72 + scol)      = k0v;
    *(int4*)(Ks[0] + (srow+32)*72 + scol) = k1v;
    *(int4*)(Vt[0] + srow*72 + scol)      = v0v;
    *(int4*)(Vt[0] + (srow+32)*72 + scol) = v1v;
  }
  __syncthreads();

  for (int kt = 0; kt <= qtA; ++kt) {
    const int cur = kt & 1;
    int4 rk0, rk1, rv0, rv1;
    if (kt < qtA) {    // prefetch next tile; loads fly during compute
      const int k0n = (kt + 1) * 64;
      rk0 = *(const int4*)(kb + base + (size_t)(k0n + srow) * Dc + scol);
      rk1 = *(const int4*)(kb + base + (size_t)(k0n + srow + 32) * Dc + scol);
      rv0 = *(const int4*)(vT + base + (size_t)srow * Tc + k0n + scol);
      rv1 = *(const int4*)(vT + base + (size_t)(srow + 32) * Tc + k0n + scol);
    }
    attn_substep(Ks[cur], Vt[cur], pw, qaA0, qaA1, oA, mA, lA, kt*64, myqA, kt == qtA, ln, qd);
    if (kt <= qtB)
      attn_substep(Ks[cur], Vt[cur], pw, qaB0, qaB1, oB, mB, lB, kt*64, myqB, kt == qtB, ln, qd);
    if (kt < qtA) {    // write next tile into idle buffer, single barrier
      const int nxt = cur ^ 1;
      *(int4*)(Ks[nxt] + srow*72 + scol)      = rk0;
      *(int4*)(Ks[nxt] + (srow+32)*72 + scol) = rk1;
      *(int4*)(Vt[nxt] + srow*72 + scol)      = rv0;
      *(int4*)(Vt[nxt] + (srow+32)*72 + scol) = rv1;
      __syncthreads();
    }
  }
  // epilogues
  float invA = 1.0f / lA, invB = 1.0f / lB;
  for (int dt = 0; dt < 4; ++dt) {
    uint2 ovA, ovB;
    ovA.x = pk_bf16(oA[dt][0] * invA, oA[dt][1] * invA);
    ovA.y = pk_bf16(oA[dt][2] * invA, oA[dt][3] * invA);
    *(uint2*)(ob + (size_t)(b*Tc + myqA)*Cc + h*Dc + dt*16 + qd*4) = ovA;
    ovB.x = pk_bf16(oB[dt][0] * invB, oB[dt][1] * invB);
    ovB.y = pk_bf16(oB[dt][2] * invB, oB[dt][3] * invB);
    *(uint2*)(ob + (size_t)(b*Tc + myqB)*Cc + h*Dc + dt*16 + qd*4) = ovB;
  }
}

extern "C" void kernel_launch(void* const* d_in, const int* in_sizes, int n_in,
                              void* d_out, int out_size, void* d_ws, size_t ws_size,
                              hipStream_t stream) {
  const float* x    = (const float*)d_in[0];
  const float* Wqkv = (const float*)d_in[1];
  const float* bqkv = (const float*)d_in[2];
  const float* Wout = (const float*)d_in[3];
  const float* bout = (const float*)d_in[4];
  float* out = (float*)d_out;

  char* ws = (char*)d_ws;
  unsigned short* xb    = (unsigned short*)ws;                    // attn output
  unsigned short* wqkvT = (unsigned short*)(ws + 8388608);
  unsigned short* woutT = (unsigned short*)(ws + 14680064);
  unsigned short* qkvb  = (unsigned short*)(ws + 16777216);

  k_prep<<<dim3(128, 32), 256, 0, stream>>>(Wqkv, Wout, wqkvT, woutT);
  k_gemm_qkv<<<dim3(N1/128, Mtot/128), 256, 0, stream>>>(x, wqkvT, bqkv, qkvb);
  k_attn<<<dim3(32, 16), 256, 0, stream>>>(qkvb, qkvb + (size_t)Bc*Hc*Tc*Dc,
                                           qkvb + (size_t)2*Bc*Hc*Tc*Dc, xb);
  k_gemm_out<<<dim3(N2/128, Mtot/64), 256, 0, stream>>>(xb, woutT, bout, out);
}

// Round 8
// 204.579 us; speedup vs baseline: 1.0945x; 1.0945x over previous
//
#include <hip/hip_runtime.h>

#define Bc 2
#define Tc 2048
#define Cc 1024
#define Hc 16
#define Dc 64
#define Mtot (Bc*Tc)   // 4096
#define Kdim Cc        // 1024
#define N1 (3*Cc)      // 3072
#define N2 Cc          // 1024

typedef __attribute__((ext_vector_type(8))) short short8;
typedef __attribute__((ext_vector_type(4))) float float4v;

__device__ __forceinline__ unsigned short f2bf(float f) {
  unsigned int u = __builtin_bit_cast(unsigned int, f);
  u += 0x7FFFu + ((u >> 16) & 1u);   // RNE
  return (unsigned short)(u >> 16);
}

// packed f32x2 -> bf16x2 (low=a, high=b)
__device__ __forceinline__ unsigned int pk_bf16(float a, float b) {
#if __has_builtin(__builtin_amdgcn_cvt_pk_bf16_f32)
  typedef __attribute__((ext_vector_type(2))) __bf16 bf16x2;
  bf16x2 v = __builtin_amdgcn_cvt_pk_bf16_f32(a, b);
  return __builtin_bit_cast(unsigned int, v);
#else
  return (unsigned int)f2bf(a) | ((unsigned int)f2bf(b) << 16);
#endif
}

// async global->LDS, 16B per lane. LDS dest must be wave-uniform base + lane*16.
__device__ __forceinline__ void gl2lds16(const unsigned short* g, unsigned short* l) {
  __builtin_amdgcn_global_load_lds((const __attribute__((address_space(1))) void*)g,
                                   (__attribute__((address_space(3))) void*)l, 16, 0, 0);
}

// ---- merged prep: weight transposes + x convert, one launch ----
// grid (256, 32): bx<96 Wqkv transpose col, bx<128 Wout transpose col,
// bx>=128 -> x fp32->bf16 (4096 blocks x 256 float4).
__global__ __launch_bounds__(256) void k_prep(const float* __restrict__ wqkv,
                                              const float* __restrict__ wout,
                                              const float* __restrict__ x,
                                              unsigned short* __restrict__ wqkvT,
                                              unsigned short* __restrict__ woutT,
                                              unsigned short* __restrict__ xb) {
  const int bx = blockIdx.x;
  if (bx >= 128) {
    int idx = ((bx - 128) * 32 + blockIdx.y) * 256 + threadIdx.x;
    float4 v = ((const float4*)x)[idx];
    uint2 o;
    o.x = pk_bf16(v.x, v.y);
    o.y = pk_bf16(v.z, v.w);
    ((uint2*)xb)[idx] = o;
    return;
  }
  __shared__ float tile[32][33];
  const float* w;  unsigned short* wT;  int N, n0;
  if (bx < 96) { w = wqkv; wT = wqkvT; N = N1; n0 = bx * 32; }
  else         { w = wout; wT = woutT; N = N2; n0 = (bx - 96) * 32; }
  const int k0 = blockIdx.y * 32;
  int tx = threadIdx.x & 31, ty = threadIdx.x >> 5;   // 32 x 8
  for (int i = 0; i < 4; ++i)
    tile[ty + 8*i][tx] = w[(size_t)(k0 + ty + 8*i) * N + n0 + tx];
  __syncthreads();
  for (int i = 0; i < 4; ++i)
    wT[(size_t)(n0 + ty + 8*i) * Kdim + k0 + tx] = f2bf(tile[tx][ty + 8*i]);
}

// ---- GEMM1: qkv = x @ Wqkv + bqkv; q,k -> [B,H,T,D], v -> [B,H,D,T] (transposed) ----
// Both A and B staged via global_load_lds (async DMA, no VGPR round-trip) — the
// R6 fp32-A fusion regressed 2x: per-iter vmcnt(0) stall on the A loads.
__global__ __launch_bounds__(256) void k_gemm_qkv(const unsigned short* __restrict__ A,
                                                  const unsigned short* __restrict__ BT,
                                                  const float* __restrict__ bias,
                                                  unsigned short* __restrict__ qkv) {
  __shared__ alignas(16) unsigned short smem[64*136 + 64];  // >= As+Bs (8192); V-bounce 64x136
  unsigned short* As = smem;
  unsigned short* Bs = smem + 4096;
  const int m0 = blockIdx.y * 128, n0 = blockIdx.x * 128;
  const int tid = threadIdx.x;
  const int w = tid >> 6, lane = tid & 63;
  const int ln = lane & 15, qd = lane >> 4;
  const int wm = w >> 1, wn = w & 1;
  const int c0 = tid, c1 = tid + 256;
  const int row0 = c0 >> 2, ko0 = (c0 & 3) * 8;
  const int row1 = c1 >> 2, ko1 = (c1 & 3) * 8;
  const float4v zero4 = {0.f, 0.f, 0.f, 0.f};
  float4v acc[4][4];
  for (int i = 0; i < 4; ++i) for (int j = 0; j < 4; ++j) acc[i][j] = zero4;
  for (int kk = 0; kk < Kdim; kk += 32) {
    __syncthreads();
    gl2lds16(A  + (size_t)(m0 + row0) * Kdim + kk + ko0, As + c0 * 8);
    gl2lds16(A  + (size_t)(m0 + row1) * Kdim + kk + ko1, As + c1 * 8);
    gl2lds16(BT + (size_t)(n0 + row0) * Kdim + kk + ko0, Bs + c0 * 8);
    gl2lds16(BT + (size_t)(n0 + row1) * Kdim + kk + ko1, Bs + c1 * 8);
    __syncthreads();
    short8 af[4], bf[4];
    for (int i = 0; i < 4; ++i)
      af[i] = *(const short8*)(As + (wm*64 + i*16 + ln) * 32 + qd*8);
    for (int j = 0; j < 4; ++j)
      bf[j] = *(const short8*)(Bs + (wn*64 + j*16 + ln) * 32 + qd*8);
    for (int i = 0; i < 4; ++i)
      for (int j = 0; j < 4; ++j)
        acc[i][j] = __builtin_amdgcn_mfma_f32_16x16x32_bf16(af[i], bf[j], acc[i][j], 0, 0, 0);
  }
  const int s = n0 >> 10;
  if (s < 2) {
    const float scale = (s == 0) ? 0.125f : 1.0f;
    for (int i = 0; i < 4; ++i) {
      int mbase = m0 + wm*64 + i*16 + qd*4;
      for (int j = 0; j < 4; ++j) {
        int ncol = n0 + wn*64 + j*16 + ln;
        float bv = bias[ncol];
        int rem = ncol & 1023;
        int h = rem >> 6, d = rem & 63;
        for (int r = 0; r < 4; ++r) {
          int m = mbase + r;
          int b = m >> 11, t = m & 2047;
          float val = (acc[i][j][r] + bv) * scale;
          qkv[((((size_t)s*Bc + b)*Hc + h)*Tc + t)*Dc + d] = f2bf(val);
        }
      }
    }
  } else {
    // V: two head-phases through LDS for coalesced [D,T] stores
    unsigned short* vbase = qkv + (size_t)2*Bc*Hc*Tc*Dc;
    const int b = m0 >> 11, t0 = m0 & 2047;
    const int h0 = (n0 & 1023) >> 6;
    for (int p = 0; p < 2; ++p) {
      __syncthreads();
      if (wn == p) {
        for (int i = 0; i < 4; ++i) {
          int tl = wm*64 + i*16 + qd*4;
          for (int j = 0; j < 4; ++j) {
            int dl = j*16 + ln;
            float bv = bias[n0 + p*64 + dl];
            uint2 pk;
            pk.x = pk_bf16(acc[i][j][0] + bv, acc[i][j][1] + bv);
            pk.y = pk_bf16(acc[i][j][2] + bv, acc[i][j][3] + bv);
            *(uint2*)(smem + dl*136 + tl) = pk;
          }
        }
      }
      __syncthreads();
      for (int ii = 0; ii < 4; ++ii) {
        int idx = tid + 256*ii;
        int row = idx >> 4, c16 = idx & 15;
        int4 v = *(const int4*)(smem + row*136 + c16*8);
        *(int4*)(vbase + (((size_t)b*Hc + h0 + p)*Dc + row)*Tc + t0 + c16*8) = v;
      }
    }
  }
}

// ---- GEMM2: out = attn @ Wout + bout, fp32 out. 64x128 tile -> 512 blocks (2/CU) ----
__global__ __launch_bounds__(256) void k_gemm_out(const unsigned short* __restrict__ A,
                                                  const unsigned short* __restrict__ BT,
                                                  const float* __restrict__ bias,
                                                  float* __restrict__ out) {
  __shared__ alignas(16) unsigned short As[64*32];    // 64 m-rows x 32 k
  __shared__ alignas(16) unsigned short Bs[128*32];   // 128 n-rows x 32 k
  const int m0 = blockIdx.y * 64, n0 = blockIdx.x * 128;
  const int tid = threadIdx.x;
  const int w = tid >> 6, lane = tid & 63;
  const int ln = lane & 15, qd = lane >> 4;
  const int wm = w >> 1, wn = w & 1;                  // wave = 32 m x 64 n
  const int arow = tid >> 2, ako = (tid & 3) * 8;     // As: 256 int4, 1/thread
  const int c0 = tid, c1 = tid + 256;                 // Bs: 512 int4, 2/thread
  const int brow0 = c0 >> 2, bko0 = (c0 & 3) * 8;
  const int brow1 = c1 >> 2, bko1 = (c1 & 3) * 8;
  const float4v zero4 = {0.f, 0.f, 0.f, 0.f};
  float4v acc[2][4];
  for (int i = 0; i < 2; ++i) for (int j = 0; j < 4; ++j) acc[i][j] = zero4;
  for (int kk = 0; kk < Kdim; kk += 32) {
    __syncthreads();
    gl2lds16(A  + (size_t)(m0 + arow)  * Kdim + kk + ako,  As + tid * 8);
    gl2lds16(BT + (size_t)(n0 + brow0) * Kdim + kk + bko0, Bs + c0 * 8);
    gl2lds16(BT + (size_t)(n0 + brow1) * Kdim + kk + bko1, Bs + c1 * 8);
    __syncthreads();
    short8 af[2], bf[4];
    for (int i = 0; i < 2; ++i)
      af[i] = *(const short8*)(As + (wm*32 + i*16 + ln) * 32 + qd*8);
    for (int j = 0; j < 4; ++j)
      bf[j] = *(const short8*)(Bs + (wn*64 + j*16 + ln) * 32 + qd*8);
    for (int i = 0; i < 2; ++i)
      for (int j = 0; j < 4; ++j)
        acc[i][j] = __builtin_amdgcn_mfma_f32_16x16x32_bf16(af[i], bf[j], acc[i][j], 0, 0, 0);
  }
  for (int i = 0; i < 2; ++i) {
    int mbase = m0 + wm*32 + i*16 + qd*4;
    for (int j = 0; j < 4; ++j) {
      int ncol = n0 + wn*64 + j*16 + ln;
      float bv = bias[ncol];
      for (int r = 0; r < 4; ++r)
        out[(size_t)(mbase + r) * N2 + ncol] = acc[i][j][r] + bv;
    }
  }
}

// ---- one online-softmax sub-step for a 16-q-row group against keys [k0,k0+64) ----
__device__ __forceinline__ void attn_substep(
    const unsigned short* __restrict__ Ks, const unsigned short* __restrict__ Vt,
    unsigned short* __restrict__ pw,
    const short8 qa0, const short8 qa1,
    float4v* o, float& m_i, float& l_i,
    int k0, int myq, bool mask, int ln, int qd)
{
  const float L2E = 1.44269504f;
  const float4v zero4 = {0.f, 0.f, 0.f, 0.f};
  float4v s[4];
  for (int ki = 0; ki < 4; ++ki) {
    s[ki] = zero4;
    const unsigned short* kr = Ks + (ki*16 + ln)*72;
    short8 kf0 = *(const short8*)(kr + qd*8);
    short8 kf1 = *(const short8*)(kr + 32 + qd*8);
    s[ki] = __builtin_amdgcn_mfma_f32_16x16x32_bf16(kf0, qa0, s[ki], 0, 0, 0);
    s[ki] = __builtin_amdgcn_mfma_f32_16x16x32_bf16(kf1, qa1, s[ki], 0, 0, 0);
  }
  if (mask) {
    for (int ki = 0; ki < 4; ++ki) {
      int key = k0 + ki*16 + qd*4;
      for (int r = 0; r < 4; ++r)
        if (key + r > myq) s[ki][r] = -1e30f;
    }
  }
  float mt = -1e30f;
  for (int ki = 0; ki < 4; ++ki)
    for (int r = 0; r < 4; ++r) mt = fmaxf(mt, s[ki][r]);
  mt = fmaxf(mt, __shfl_xor(mt, 16));
  mt = fmaxf(mt, __shfl_xor(mt, 32));
  float mn = fmaxf(m_i, mt);
  float al = exp2f((m_i - mn) * L2E);
  m_i = mn;
  float st = 0.f;
  for (int ki = 0; ki < 4; ++ki)
    for (int r = 0; r < 4; ++r) {
      s[ki][r] = exp2f((s[ki][r] - mn) * L2E);
      st += s[ki][r];
    }
  st += __shfl_xor(st, 16);
  st += __shfl_xor(st, 32);
  l_i = l_i * al + st;
  for (int dt = 0; dt < 4; ++dt)
    for (int r = 0; r < 4; ++r) o[dt][r] *= al;
  // P: C/D -> A-operand layout via per-wave LDS buffer (DS in-order per wave)
  for (int ki = 0; ki < 4; ++ki) {
    uint2 p2;
    p2.x = pk_bf16(s[ki][0], s[ki][1]);
    p2.y = pk_bf16(s[ki][2], s[ki][3]);
    *(uint2*)(pw + ln*72 + ki*16 + qd*4) = p2;
  }
  short8 pb0 = *(const short8*)(pw + ln*72 + qd*8);
  short8 pb1 = *(const short8*)(pw + ln*72 + 32 + qd*8);
  for (int dt = 0; dt < 4; ++dt) {
    const unsigned short* vr = Vt + (dt*16 + ln)*72;
    short8 va0 = *(const short8*)(vr + qd*8);
    short8 va1 = *(const short8*)(vr + 32 + qd*8);
    o[dt] = __builtin_amdgcn_mfma_f32_16x16x32_bf16(va0, pb0, o[dt], 0, 0, 0);
    o[dt] = __builtin_amdgcn_mfma_f32_16x16x32_bf16(va1, pb1, o[dt], 0, 0, 0);
  }
}

// ---- flash-style causal attention: dual q-tiles per block, double-buffered K/V ----
// grid (32 bh, 16 pp). Block owns q-tiles A=31-pp (heavy) and B=pp (light) -> 33
// uniform sub-steps. K/V double-buffered in LDS: ONE barrier per kt. Next tile's
// K/V register-prefetched and written into the idle buffer.
__global__ __launch_bounds__(256) void k_attn(const unsigned short* __restrict__ qb,
                                              const unsigned short* __restrict__ kb,
                                              const unsigned short* __restrict__ vT,
                                              unsigned short* __restrict__ ob) {
  __shared__ alignas(16) unsigned short Ks[2][64*72];  // [key][d], stride 72
  __shared__ alignas(16) unsigned short Vt[2][64*72];  // [d][key], stride 72
  __shared__ alignas(16) unsigned short Ps[4][16*72];  // per-wave P, stride 72
  const int bh = blockIdx.x;
  const int pp = blockIdx.y;
  const int qtA = 31 - pp, qtB = pp;
  const int tid = threadIdx.x;
  const int w = tid >> 6, lane = tid & 63;
  const int ln = lane & 15, qd = lane >> 4;
  const size_t base = (size_t)bh * Tc * Dc;
  const int b = bh >> 4, h = bh & 15;
  const int srow = tid >> 3, scol = (tid & 7) * 8;     // staging: 32 rows x 8 int4
  const float4v zero4 = {0.f, 0.f, 0.f, 0.f};
  unsigned short* pw = Ps[w];

  const int myqA = qtA*64 + w*16 + ln;
  const int myqB = qtB*64 + w*16 + ln;
  const unsigned short* qrA = qb + base + (size_t)myqA * Dc;
  const unsigned short* qrB = qb + base + (size_t)myqB * Dc;
  short8 qaA0 = *(const short8*)(qrA + qd*8);
  short8 qaA1 = *(const short8*)(qrA + 32 + qd*8);
  short8 qaB0 = *(const short8*)(qrB + qd*8);
  short8 qaB1 = *(const short8*)(qrB + 32 + qd*8);
  float4v oA[4], oB[4];
  for (int dt = 0; dt < 4; ++dt) { oA[dt] = zero4; oB[dt] = zero4; }
  float mA = -1e30f, lA = 0.f, mB = -1e30f, lB = 0.f;

  // stage kt=0 into buffer 0
  {
    int4 k0v = *(const int4*)(kb + base + (size_t)srow * Dc + scol);
    int4 k1v = *(const int4*)(kb + base + (size_t)(srow + 32) * Dc + scol);
    int4 v0v = *(const int4*)(vT + base + (size_t)srow * Tc + scol);
    int4 v1v = *(const int4*)(vT + base + (size_t)(srow + 32) * Tc + scol);
    *(int4*)(Ks[0] + srow*72 + scol)      = k0v;
    *(int4*)(Ks[0] + (srow+32)*72 + scol) = k1v;
    *(int4*)(Vt[0] + srow*72 + scol)      = v0v;
    *(int4*)(Vt[0] + (srow+32)*72 + scol) = v1v;
  }
  __syncthreads();

  for (int kt = 0; kt <= qtA; ++kt) {
    const int cur = kt & 1;
    int4 rk0, rk1, rv0, rv1;
    if (kt < qtA) {    // prefetch next tile; loads fly during compute
      const int k0n = (kt + 1) * 64;
      rk0 = *(const int4*)(kb + base + (size_t)(k0n + srow) * Dc + scol);
      rk1 = *(const int4*)(kb + base + (size_t)(k0n + srow + 32) * Dc + scol);
      rv0 = *(const int4*)(vT + base + (size_t)srow * Tc + k0n + scol);
      rv1 = *(const int4*)(vT + base + (size_t)(srow + 32) * Tc + k0n + scol);
    }
    attn_substep(Ks[cur], Vt[cur], pw, qaA0, qaA1, oA, mA, lA, kt*64, myqA, kt == qtA, ln, qd);
    if (kt <= qtB)
      attn_substep(Ks[cur], Vt[cur], pw, qaB0, qaB1, oB, mB, lB, kt*64, myqB, kt == qtB, ln, qd);
    if (kt < qtA) {    // write next tile into idle buffer, single barrier
      const int nxt = cur ^ 1;
      *(int4*)(Ks[nxt] + srow*72 + scol)      = rk0;
      *(int4*)(Ks[nxt] + (srow+32)*72 + scol) = rk1;
      *(int4*)(Vt[nxt] + srow*72 + scol)      = rv0;
      *(int4*)(Vt[nxt] + (srow+32)*72 + scol) = rv1;
      __syncthreads();
    }
  }
  // epilogues
  float invA = 1.0f / lA, invB = 1.0f / lB;
  for (int dt = 0; dt < 4; ++dt) {
    uint2 ovA, ovB;
    ovA.x = pk_bf16(oA[dt][0] * invA, oA[dt][1] * invA);
    ovA.y = pk_bf16(oA[dt][2] * invA, oA[dt][3] * invA);
    *(uint2*)(ob + (size_t)(b*Tc + myqA)*Cc + h*Dc + dt*16 + qd*4) = ovA;
    ovB.x = pk_bf16(oB[dt][0] * invB, oB[dt][1] * invB);
    ovB.y = pk_bf16(oB[dt][2] * invB, oB[dt][3] * invB);
    *(uint2*)(ob + (size_t)(b*Tc + myqB)*Cc + h*Dc + dt*16 + qd*4) = ovB;
  }
}

extern "C" void kernel_launch(void* const* d_in, const int* in_sizes, int n_in,
                              void* d_out, int out_size, void* d_ws, size_t ws_size,
                              hipStream_t stream) {
  const float* x    = (const float*)d_in[0];
  const float* Wqkv = (const float*)d_in[1];
  const float* bqkv = (const float*)d_in[2];
  const float* Wout = (const float*)d_in[3];
  const float* bout = (const float*)d_in[4];
  float* out = (float*)d_out;

  char* ws = (char*)d_ws;
  unsigned short* xb    = (unsigned short*)ws;                    // x bf16, later attn out
  unsigned short* wqkvT = (unsigned short*)(ws + 8388608);
  unsigned short* woutT = (unsigned short*)(ws + 14680064);
  unsigned short* qkvb  = (unsigned short*)(ws + 16777216);

  k_prep<<<dim3(256, 32), 256, 0, stream>>>(Wqkv, Wout, x, wqkvT, woutT, xb);
  k_gemm_qkv<<<dim3(N1/128, Mtot/128), 256, 0, stream>>>(xb, wqkvT, bqkv, qkvb);
  k_attn<<<dim3(32, 16), 256, 0, stream>>>(qkvb, qkvb + (size_t)Bc*Hc*Tc*Dc,
                                           qkvb + (size_t)2*Bc*Hc*Tc*Dc, xb);
  k_gemm_out<<<dim3(N2/128, Mtot/64), 256, 0, stream>>>(xb, woutT, bout, out);
}